// Round 1
// baseline (648.639 us; speedup 1.0000x reference)
//
#include <hip/hip_runtime.h>
#include <hip/hip_bf16.h>

// MoE top-2, d=1024, E=8, N=8192 tokens. Grouped-GEMM design:
//   cast/transposes -> gate(top2) -> plan(pad slots to BM) -> fill -> GEMM1(relu) -> GEMM2(+atomic combine)
// bf16 MFMA 16x16x32, 128x128 tiles, 4 waves x 4x4 frags.

#define NTOK   8192
#define DM     1024
#define NE     8
#define BM     128
#define NSLOT  (NTOK * 2)
#define PADCAP (NSLOT + NE * BM)      // 17408
#define MAXTILES (PADCAP / BM)        // 136

typedef __attribute__((ext_vector_type(8))) short  bf16x8;
typedef __attribute__((ext_vector_type(4))) float  f32x4;

__device__ __forceinline__ unsigned short f2bf(float f) {
    union { float f; unsigned u; } v; v.f = f;
    unsigned r = v.u + 0x7fffu + ((v.u >> 16) & 1u);
    return (unsigned short)(r >> 16);
}

// ---------- cast x (fp32 -> bf16), 4 elems/thread ----------
__global__ __launch_bounds__(256) void k_cast_x(const float* __restrict__ x,
                                                ushort* __restrict__ xb) {
    int i = blockIdx.x * 256 + threadIdx.x;   // i < NTOK*DM/4
    float4 v = ((const float4*)x)[i];
    ushort4 o;
    o.x = f2bf(v.x); o.y = f2bf(v.y); o.z = f2bf(v.z); o.w = f2bf(v.w);
    ((ushort4*)xb)[i] = o;
}

// ---------- transpose + cast weights: Wt[e][n][k] = W[e][k][n] ----------
__global__ __launch_bounds__(256) void k_transpose(const float* __restrict__ W,
                                                   ushort* __restrict__ Wt) {
    __shared__ float t[32][33];
    int e = blockIdx.z;
    const float* We = W + (size_t)e * DM * DM;
    ushort* Wte = Wt + (size_t)e * DM * DM;
    int kt = blockIdx.y * 32, nt = blockIdx.x * 32;
    int tx = threadIdx.x, ty = threadIdx.y;
#pragma unroll
    for (int i = 0; i < 4; i++) {
        int r = ty + i * 8;
        t[r][tx] = We[(size_t)(kt + r) * DM + nt + tx];
    }
    __syncthreads();
#pragma unroll
    for (int i = 0; i < 4; i++) {
        int r = ty + i * 8;
        Wte[(size_t)(nt + r) * DM + kt + tx] = f2bf(t[tx][r]);
    }
}

// ---------- gating: scores = x@Wg + bg (fp32 exact), top-2, counts ----------
__global__ __launch_bounds__(256) void k_gate(const float* __restrict__ x,
                                              const float* __restrict__ Wg,
                                              const float* __restrict__ bg,
                                              int* __restrict__ tok_e,
                                              float* __restrict__ tok_w,
                                              int* __restrict__ counts) {
    __shared__ float wg[DM * NE];   // 32 KB
    int tid = threadIdx.x;
    for (int i = tid; i < DM * NE / 4; i += 256)
        ((float4*)wg)[i] = ((const float4*)Wg)[i];
    __syncthreads();
    int wave = tid >> 6, lane = tid & 63;
    int n = blockIdx.x * 4 + wave;
    const float* xr = x + (size_t)n * DM;
    float acc[NE];
#pragma unroll
    for (int e = 0; e < NE; e++) acc[e] = 0.f;
    for (int j = 0; j < 16; j++) {
        int d = j * 64 + lane;
        float xv = xr[d];
        const float* wr = &wg[d * NE];
#pragma unroll
        for (int e = 0; e < NE; e++) acc[e] += xv * wr[e];
    }
#pragma unroll
    for (int e = 0; e < NE; e++) {
#pragma unroll
        for (int off = 32; off >= 1; off >>= 1)
            acc[e] += __shfl_xor(acc[e], off);
    }
    if (lane == 0) {
        float sc[NE];
#pragma unroll
        for (int e = 0; e < NE; e++) sc[e] = acc[e] + bg[e];
        int e0 = 0; float v0 = sc[0];
#pragma unroll
        for (int e = 1; e < NE; e++) if (sc[e] > v0) { v0 = sc[e]; e0 = e; }
        int e1 = -1; float v1 = -3.0e38f;
#pragma unroll
        for (int e = 0; e < NE; e++) if (e != e0 && sc[e] > v1) { v1 = sc[e]; e1 = e; }
        tok_e[2 * n] = e0;     tok_w[2 * n] = v0;
        tok_e[2 * n + 1] = e1; tok_w[2 * n + 1] = v1;
        atomicAdd(&counts[e0], 1);
        atomicAdd(&counts[e1], 1);
    }
}

// ---------- plan: padded bases + tile tables (serial, trivial) ----------
__global__ void k_plan(const int* __restrict__ counts, int* __restrict__ base,
                       int* __restrict__ cursor, int* __restrict__ tile_e,
                       int* __restrict__ tile_b, int* __restrict__ ntiles) {
    if (threadIdx.x == 0 && blockIdx.x == 0) {
        int off = 0, t = 0;
        for (int e = 0; e < NE; e++) {
            base[e] = off; cursor[e] = 0;
            int nt = (counts[e] + BM - 1) / BM;
            for (int i = 0; i < nt; i++) { tile_e[t] = e; tile_b[t] = off + i * BM; t++; }
            off += nt * BM;
        }
        *ntiles = t;
    }
}

// ---------- fill: scatter (token, weight) into expert slot ranges ----------
__global__ __launch_bounds__(256) void k_fill(const int* __restrict__ tok_e,
                                              const float* __restrict__ tok_w,
                                              const int* __restrict__ base,
                                              int* __restrict__ cursor,
                                              int* __restrict__ slot_token,
                                              float* __restrict__ slot_w) {
    int n = blockIdx.x * 256 + threadIdx.x;
#pragma unroll
    for (int k = 0; k < 2; k++) {
        int e = tok_e[2 * n + k];
        float w = tok_w[2 * n + k];
        int pos = atomicAdd(&cursor[e], 1);
        int s = base[e] + pos;
        slot_token[s] = n;
        slot_w[s] = w;
    }
}

// ---------- grouped GEMM: 128x128 tile, BK=64, 4 waves x (64x64 each) ----------
// PHASE 1: H = relu(Xg @ W1t^T + b1)   (store bf16)
// PHASE 2: out[token] += w * (H @ W2t^T + b2)   (fp32 atomicAdd)
template <int PHASE>
__global__ __launch_bounds__(256) void k_gemm(const ushort* __restrict__ A,
                                              const ushort* __restrict__ Wt,
                                              const float* __restrict__ bias,
                                              const int* __restrict__ slot_token,
                                              const float* __restrict__ slot_w,
                                              const int* __restrict__ tile_e,
                                              const int* __restrict__ tile_b,
                                              const int* __restrict__ ntiles,
                                              ushort* __restrict__ Hout,
                                              float* __restrict__ out) {
    int t = blockIdx.y;
    if (t >= *ntiles) return;
    int e = tile_e[t];
    int sbase = tile_b[t];
    int ncol0 = blockIdx.x * 128;

    __shared__ ushort As[128][72];   // +8 pad: rows 16B-aligned, 2-way-only bank alias
    __shared__ ushort Bs[128][72];

    int tid = threadIdx.x;
    int wave = tid >> 6, lane = tid & 63, quad = lane >> 4, lm = lane & 15;
    int wm = wave >> 1, wn = wave & 1;

    // staging role: thread handles rows srow + p*32 (p=0..3), 8 bf16 at k-offset skc
    int srow = tid >> 3;          // 0..31
    int skc = (tid & 7) * 8;      // 0..56

    int arow[4];
#pragma unroll
    for (int p = 0; p < 4; p++) {
        int row = srow + p * 32;
        if (PHASE == 1) arow[p] = slot_token[sbase + row];   // -1 for pad rows
        else            arow[p] = sbase + row;               // H indexed by slot
    }

    f32x4 acc[4][4];
#pragma unroll
    for (int i = 0; i < 4; i++)
#pragma unroll
        for (int j = 0; j < 4; j++) acc[i][j] = (f32x4){0.f, 0.f, 0.f, 0.f};

    const ushort* Wte = Wt + (size_t)e * DM * DM;

    for (int k0 = 0; k0 < DM; k0 += 64) {
        __syncthreads();   // protect LDS from previous iteration's readers
#pragma unroll
        for (int p = 0; p < 4; p++) {
            int row = srow + p * 32;
            uint4 va = make_uint4(0u, 0u, 0u, 0u);
            if (arow[p] >= 0)
                va = *(const uint4*)(A + (size_t)arow[p] * DM + k0 + skc);
            *(uint4*)&As[row][skc] = va;
            uint4 vb = *(const uint4*)(Wte + (size_t)(ncol0 + row) * DM + k0 + skc);
            *(uint4*)&Bs[row][skc] = vb;
        }
        __syncthreads();
#pragma unroll
        for (int ks = 0; ks < 2; ks++) {
            bf16x8 av[4], bv[4];
#pragma unroll
            for (int f = 0; f < 4; f++) {
                av[f] = *(const bf16x8*)&As[wm * 64 + f * 16 + lm][ks * 32 + quad * 8];
                bv[f] = *(const bf16x8*)&Bs[wn * 64 + f * 16 + lm][ks * 32 + quad * 8];
            }
#pragma unroll
            for (int fm = 0; fm < 4; fm++)
#pragma unroll
                for (int fn = 0; fn < 4; fn++)
                    acc[fm][fn] = __builtin_amdgcn_mfma_f32_16x16x32_bf16(
                        av[fm], bv[fn], acc[fm][fn], 0, 0, 0);
        }
    }

    // epilogue — C/D layout: col = lane&15, row = quad*4 + r  [m89-verified]
#pragma unroll
    for (int fm = 0; fm < 4; fm++) {
        int rowg = wm * 64 + fm * 16 + quad * 4;
        if (PHASE == 1) {
#pragma unroll
            for (int fn = 0; fn < 4; fn++) {
                int col = ncol0 + wn * 64 + fn * 16 + lm;
                float bv2 = bias[e * DM + col];
#pragma unroll
                for (int r = 0; r < 4; r++) {
                    float v = acc[fm][fn][r] + bv2;
                    v = fmaxf(v, 0.f);
                    Hout[(size_t)(sbase + rowg + r) * DM + col] = f2bf(v);
                }
            }
        } else {
            int tk[4]; float wv[4];
#pragma unroll
            for (int r = 0; r < 4; r++) {
                tk[r] = slot_token[sbase + rowg + r];
                wv[r] = slot_w[sbase + rowg + r];
            }
#pragma unroll
            for (int fn = 0; fn < 4; fn++) {
                int col = ncol0 + wn * 64 + fn * 16 + lm;
                float bv2 = bias[e * DM + col];
#pragma unroll
                for (int r = 0; r < 4; r++) {
                    if (tk[r] >= 0) {
                        float v = wv[r] * (acc[fm][fn][r] + bv2);
                        atomicAdd(&out[(size_t)tk[r] * DM + col], v);
                    }
                }
            }
        }
    }
}

extern "C" void kernel_launch(void* const* d_in, const int* in_sizes, int n_in,
                              void* d_out, int out_size, void* d_ws, size_t ws_size,
                              hipStream_t stream) {
    const float* x  = (const float*)d_in[0];
    const float* Wg = (const float*)d_in[1];
    const float* bg = (const float*)d_in[2];
    const float* W1 = (const float*)d_in[3];
    const float* b1 = (const float*)d_in[4];
    const float* W2 = (const float*)d_in[5];
    const float* b2 = (const float*)d_in[6];
    float* out = (float*)d_out;

    char* ws = (char*)d_ws;
    // workspace layout (bytes) — total ~86.3 MB
    ushort* xb         = (ushort*)(ws + 0);            // 16 MB
    ushort* w1t        = (ushort*)(ws + 16777216);     // 16 MB
    ushort* w2t        = (ushort*)(ws + 33554432);     // 16 MB
    ushort* H          = (ushort*)(ws + 50331648);     // 34 MB (PADCAP*DM*2)
    int*    tok_e      = (int*)  (ws + 85983232);
    float*  tok_w      = (float*)(ws + 86048768);
    int*    slot_token = (int*)  (ws + 86114304);
    float*  slot_w     = (float*)(ws + 86183936);
    int*    counts     = (int*)  (ws + 86253568);
    int*    cursor     = counts + 8;
    int*    base       = counts + 16;
    int*    tile_e     = counts + 24;
    int*    tile_b     = tile_e + MAXTILES;
    int*    ntiles     = tile_b + MAXTILES;

    hipMemsetAsync(counts, 0, 16 * sizeof(int), stream);          // counts + cursor
    hipMemsetAsync(slot_token, 0xFF, PADCAP * sizeof(int), stream);   // -1 sentinels
    hipMemsetAsync(out, 0, (size_t)NTOK * DM * sizeof(float), stream);

    k_cast_x<<<NTOK * DM / 1024, 256, 0, stream>>>(x, xb);
    dim3 tb(32, 8);
    dim3 tg(32, 32, NE);
    k_transpose<<<tg, tb, 0, stream>>>(W1, w1t);
    k_transpose<<<tg, tb, 0, stream>>>(W2, w2t);
    k_gate<<<NTOK / 4, 256, 0, stream>>>(x, Wg, bg, tok_e, tok_w, counts);
    k_plan<<<1, 64, 0, stream>>>(counts, base, cursor, tile_e, tile_b, ntiles);
    k_fill<<<NTOK / 256, 256, 0, stream>>>(tok_e, tok_w, base, cursor, slot_token, slot_w);

    dim3 gg(DM / 128, MAXTILES);
    k_gemm<1><<<gg, 256, 0, stream>>>(xb, w1t, b1, slot_token, slot_w,
                                      tile_e, tile_b, ntiles, H, nullptr);
    k_gemm<2><<<gg, 256, 0, stream>>>(H, w2t, b2, slot_token, slot_w,
                                      tile_e, tile_b, ntiles, nullptr, out);
}

// Round 2
// 537.911 us; speedup vs baseline: 1.2058x; 1.2058x over previous
//
#include <hip/hip_runtime.h>
#include <hip/hip_bf16.h>

// MoE top-2, d=1024, E=8, N=8192 tokens. Grouped-GEMM design:
//   cast/transposes -> gate(top2) -> plan(pad slots to BM) -> fill -> GEMM1(relu) -> GEMM2(+atomic combine)
// R1: gate rewritten (transposed Wg in LDS, float4, 4 tok/wave) — was 194us w/ 1M bank conflicts.
//     GEMM staging -> global_load_lds width=16 into [kblock][row][8] LDS layout (m97 ladder rung).

#define NTOK   8192
#define DM     1024
#define NE     8
#define BM     128
#define NSLOT  (NTOK * 2)
#define PADCAP (NSLOT + NE * BM)      // 17408
#define MAXTILES (PADCAP / BM)        // 136

typedef __attribute__((ext_vector_type(8))) short  bf16x8;
typedef __attribute__((ext_vector_type(4))) float  f32x4;

__device__ __forceinline__ unsigned short f2bf(float f) {
    union { float f; unsigned u; } v; v.f = f;
    unsigned r = v.u + 0x7fffu + ((v.u >> 16) & 1u);
    return (unsigned short)(r >> 16);
}

// async global->LDS DMA, 16B per lane; dest = wave-uniform base + lane*16
__device__ __forceinline__ void load_lds16(const ushort* g, ushort* l) {
    __builtin_amdgcn_global_load_lds(
        (const __attribute__((address_space(1))) unsigned int*)g,
        (__attribute__((address_space(3))) unsigned int*)l,
        16, 0, 0);
}

// ---------- cast x (fp32 -> bf16), 4 elems/thread ----------
__global__ __launch_bounds__(256) void k_cast_x(const float* __restrict__ x,
                                                ushort* __restrict__ xb) {
    int i = blockIdx.x * 256 + threadIdx.x;   // i < NTOK*DM/4
    float4 v = ((const float4*)x)[i];
    ushort4 o;
    o.x = f2bf(v.x); o.y = f2bf(v.y); o.z = f2bf(v.z); o.w = f2bf(v.w);
    ((ushort4*)xb)[i] = o;
}

// ---------- transpose + cast weights: Wt[e][n][k] = W[e][k][n] ----------
__global__ __launch_bounds__(256) void k_transpose(const float* __restrict__ W,
                                                   ushort* __restrict__ Wt) {
    __shared__ float t[32][33];
    int e = blockIdx.z;
    const float* We = W + (size_t)e * DM * DM;
    ushort* Wte = Wt + (size_t)e * DM * DM;
    int kt = blockIdx.y * 32, nt = blockIdx.x * 32;
    int tx = threadIdx.x, ty = threadIdx.y;
#pragma unroll
    for (int i = 0; i < 4; i++) {
        int r = ty + i * 8;
        t[r][tx] = We[(size_t)(kt + r) * DM + nt + tx];
    }
    __syncthreads();
#pragma unroll
    for (int i = 0; i < 4; i++) {
        int r = ty + i * 8;
        Wte[(size_t)(nt + r) * DM + kt + tx] = f2bf(t[tx][r]);
    }
}

// ---------- gating: scores = x@Wg + bg (fp32 exact), top-2, counts ----------
// 4 waves/block, 4 tokens/wave -> 16 tokens/block, 512 blocks.
__global__ __launch_bounds__(256) void k_gate(const float* __restrict__ x,
                                              const float* __restrict__ Wg,
                                              const float* __restrict__ bg,
                                              int* __restrict__ tok_e,
                                              float* __restrict__ tok_w,
                                              int* __restrict__ counts) {
    __shared__ float wgT[NE][DM];   // 32 KB, transposed: wgT[e][d] = Wg[d][e]
    __shared__ int cnt[NE];
    int tid = threadIdx.x;
    if (tid < NE) cnt[tid] = 0;
    for (int i = tid; i < DM * NE; i += 256) {
        int d = i >> 3, e = i & 7;
        wgT[e][d] = Wg[i];
    }
    __syncthreads();
    int wave = tid >> 6, lane = tid & 63;
    int n0 = (blockIdx.x * 4 + wave) * 4;
    const float4* xr[4];
#pragma unroll
    for (int t = 0; t < 4; t++) xr[t] = (const float4*)(x + (size_t)(n0 + t) * DM);

    float acc[4][NE];
#pragma unroll
    for (int t = 0; t < 4; t++)
#pragma unroll
        for (int e = 0; e < NE; e++) acc[t][e] = 0.f;

#pragma unroll
    for (int j = 0; j < 4; j++) {
        float4 xv[4];
#pragma unroll
        for (int t = 0; t < 4; t++) xv[t] = xr[t][j * 64 + lane];
#pragma unroll
        for (int e = 0; e < NE; e++) {
            float4 wv = ((const float4*)&wgT[e][0])[j * 64 + lane];
#pragma unroll
            for (int t = 0; t < 4; t++) {
                acc[t][e] += xv[t].x * wv.x + xv[t].y * wv.y
                           + xv[t].z * wv.z + xv[t].w * wv.w;
            }
        }
    }
    // butterfly reduce all 32 accumulators across 64 lanes
#pragma unroll
    for (int t = 0; t < 4; t++)
#pragma unroll
        for (int e = 0; e < NE; e++) {
#pragma unroll
            for (int off = 32; off >= 1; off >>= 1)
                acc[t][e] += __shfl_xor(acc[t][e], off);
        }
    if (lane < 4) {
        int t = lane, n = n0 + t;
        float sc[NE];
#pragma unroll
        for (int e = 0; e < NE; e++) sc[e] = acc[t][e] + bg[e];
        int e0 = 0; float v0 = sc[0];
#pragma unroll
        for (int e = 1; e < NE; e++) if (sc[e] > v0) { v0 = sc[e]; e0 = e; }
        int e1 = -1; float v1 = -3.0e38f;
#pragma unroll
        for (int e = 0; e < NE; e++) if (e != e0 && sc[e] > v1) { v1 = sc[e]; e1 = e; }
        tok_e[2 * n] = e0;     tok_w[2 * n] = v0;
        tok_e[2 * n + 1] = e1; tok_w[2 * n + 1] = v1;
        atomicAdd(&cnt[e0], 1);
        atomicAdd(&cnt[e1], 1);
    }
    __syncthreads();
    if (tid < NE) atomicAdd(&counts[tid], cnt[tid]);
}

// ---------- plan: padded bases + tile tables (serial, trivial) ----------
__global__ void k_plan(const int* __restrict__ counts, int* __restrict__ base,
                       int* __restrict__ cursor, int* __restrict__ tile_e,
                       int* __restrict__ tile_b, int* __restrict__ ntiles) {
    if (threadIdx.x == 0 && blockIdx.x == 0) {
        int off = 0, t = 0;
        for (int e = 0; e < NE; e++) {
            base[e] = off; cursor[e] = 0;
            int nt = (counts[e] + BM - 1) / BM;
            for (int i = 0; i < nt; i++) { tile_e[t] = e; tile_b[t] = off + i * BM; t++; }
            off += nt * BM;
        }
        *ntiles = t;
    }
}

// ---------- fill: scatter (token, weight) into expert slot ranges ----------
__global__ __launch_bounds__(256) void k_fill(const int* __restrict__ tok_e,
                                              const float* __restrict__ tok_w,
                                              const int* __restrict__ base,
                                              int* __restrict__ cursor,
                                              int* __restrict__ slot_token,
                                              float* __restrict__ slot_w) {
    int n = blockIdx.x * 256 + threadIdx.x;
#pragma unroll
    for (int k = 0; k < 2; k++) {
        int e = tok_e[2 * n + k];
        float w = tok_w[2 * n + k];
        int pos = atomicAdd(&cursor[e], 1);
        int s = base[e] + pos;
        slot_token[s] = n;
        slot_w[s] = w;
    }
}

// ---------- grouped GEMM: 128x128 tile, BK=64, 4 waves x (64x64 each) ----------
// LDS layout: [kblock 0..7][row 0..127][8 bf16]  (16 KB per operand)
//   - global_load_lds: chunk (kb,h) = contiguous 1KB, lane l -> row h*64+l  (dest uniform)
//   - ds_read_b128 fragment: lane stride 16B, 8 lanes/bank-group -> optimal 8-phase
// PHASE 1: H = relu(Xg @ W1t^T + b1)   (store bf16)
// PHASE 2: out[token] += w * (H @ W2t^T + b2)   (fp32 atomicAdd)
template <int PHASE>
__global__ __launch_bounds__(256) void k_gemm(const ushort* __restrict__ A,
                                              const ushort* __restrict__ Wt,
                                              const float* __restrict__ bias,
                                              const int* __restrict__ slot_token,
                                              const float* __restrict__ slot_w,
                                              const int* __restrict__ tile_e,
                                              const int* __restrict__ tile_b,
                                              const int* __restrict__ ntiles,
                                              ushort* __restrict__ Hout,
                                              float* __restrict__ out) {
    int t = blockIdx.y;
    if (t >= *ntiles) return;
    int e = tile_e[t];
    int sbase = tile_b[t];
    int ncol0 = blockIdx.x * 128;

    __shared__ ushort AsL[8192];   // [kb][row][8]
    __shared__ ushort BsL[8192];

    int tid = threadIdx.x;
    int wave = tid >> 6, lane = tid & 63, quad = lane >> 4, lm = lane & 15;
    int wm = wave >> 1, wn = wave & 1;

    const ushort* Wte = Wt + (size_t)e * DM * DM;

    // per-lane source row pointers for the two 64-row halves
    const ushort* aptr[2];
    const ushort* bptr[2];
#pragma unroll
    for (int h = 0; h < 2; h++) {
        int row = h * 64 + lane;
        int ar;
        if (PHASE == 1) {
            ar = slot_token[sbase + row];
            if (ar < 0) ar = 0;              // pad rows: load row 0, discard in epilogue
        } else {
            ar = sbase + row;
        }
        aptr[h] = A + (size_t)ar * DM;
        bptr[h] = Wte + (size_t)(ncol0 + row) * DM;
    }

    f32x4 acc[4][4];
#pragma unroll
    for (int i = 0; i < 4; i++)
#pragma unroll
        for (int j = 0; j < 4; j++) acc[i][j] = (f32x4){0.f, 0.f, 0.f, 0.f};

    for (int k0 = 0; k0 < DM; k0 += 64) {
        // async stage this K-tile: each wave covers kblocks {2w, 2w+1} x both halves
#pragma unroll
        for (int kbi = 0; kbi < 2; kbi++) {
            int kb = wave * 2 + kbi;
            int koff = k0 + kb * 8;
            load_lds16(aptr[0] + koff, &AsL[kb * 1024]);
            load_lds16(aptr[1] + koff, &AsL[kb * 1024 + 512]);
            load_lds16(bptr[0] + koff, &BsL[kb * 1024]);
            load_lds16(bptr[1] + koff, &BsL[kb * 1024 + 512]);
        }
        __syncthreads();   // drains vmcnt: DMA complete, all waves staged
#pragma unroll
        for (int ks = 0; ks < 2; ks++) {
            bf16x8 av[4], bv[4];
#pragma unroll
            for (int f = 0; f < 4; f++) {
                av[f] = *(const bf16x8*)&AsL[(ks * 4 + quad) * 1024 + (wm * 64 + f * 16 + lm) * 8];
                bv[f] = *(const bf16x8*)&BsL[(ks * 4 + quad) * 1024 + (wn * 64 + f * 16 + lm) * 8];
            }
#pragma unroll
            for (int fm = 0; fm < 4; fm++)
#pragma unroll
                for (int fn = 0; fn < 4; fn++)
                    acc[fm][fn] = __builtin_amdgcn_mfma_f32_16x16x32_bf16(
                        av[fm], bv[fn], acc[fm][fn], 0, 0, 0);
        }
        __syncthreads();   // readers done before next iteration's DMA overwrites
    }

    // epilogue — C/D layout: col = lane&15, row = quad*4 + r  [m89-verified]
#pragma unroll
    for (int fm = 0; fm < 4; fm++) {
        int rowg = wm * 64 + fm * 16 + quad * 4;
        if (PHASE == 1) {
#pragma unroll
            for (int fn = 0; fn < 4; fn++) {
                int col = ncol0 + wn * 64 + fn * 16 + lm;
                float bv2 = bias[e * DM + col];
#pragma unroll
                for (int r = 0; r < 4; r++) {
                    float v = acc[fm][fn][r] + bv2;
                    v = fmaxf(v, 0.f);
                    Hout[(size_t)(sbase + rowg + r) * DM + col] = f2bf(v);
                }
            }
        } else {
            int tk[4]; float wv[4];
#pragma unroll
            for (int r = 0; r < 4; r++) {
                tk[r] = slot_token[sbase + rowg + r];
                wv[r] = slot_w[sbase + rowg + r];
            }
#pragma unroll
            for (int fn = 0; fn < 4; fn++) {
                int col = ncol0 + wn * 64 + fn * 16 + lm;
                float bv2 = bias[e * DM + col];
#pragma unroll
                for (int r = 0; r < 4; r++) {
                    if (tk[r] >= 0) {
                        float v = wv[r] * (acc[fm][fn][r] + bv2);
                        atomicAdd(&out[(size_t)tk[r] * DM + col], v);
                    }
                }
            }
        }
    }
}

extern "C" void kernel_launch(void* const* d_in, const int* in_sizes, int n_in,
                              void* d_out, int out_size, void* d_ws, size_t ws_size,
                              hipStream_t stream) {
    const float* x  = (const float*)d_in[0];
    const float* Wg = (const float*)d_in[1];
    const float* bg = (const float*)d_in[2];
    const float* W1 = (const float*)d_in[3];
    const float* b1 = (const float*)d_in[4];
    const float* W2 = (const float*)d_in[5];
    const float* b2 = (const float*)d_in[6];
    float* out = (float*)d_out;

    char* ws = (char*)d_ws;
    // workspace layout (bytes) — total ~86.3 MB
    ushort* xb         = (ushort*)(ws + 0);            // 16 MB
    ushort* w1t        = (ushort*)(ws + 16777216);     // 16 MB
    ushort* w2t        = (ushort*)(ws + 33554432);     // 16 MB
    ushort* H          = (ushort*)(ws + 50331648);     // 34 MB (PADCAP*DM*2)
    int*    tok_e      = (int*)  (ws + 85983232);
    float*  tok_w      = (float*)(ws + 86048768);
    int*    slot_token = (int*)  (ws + 86114304);
    float*  slot_w     = (float*)(ws + 86183936);
    int*    counts     = (int*)  (ws + 86253568);
    int*    cursor     = counts + 8;
    int*    base       = counts + 16;
    int*    tile_e     = counts + 24;
    int*    tile_b     = tile_e + MAXTILES;
    int*    ntiles     = tile_b + MAXTILES;

    hipMemsetAsync(counts, 0, 16 * sizeof(int), stream);          // counts + cursor
    hipMemsetAsync(slot_token, 0xFF, PADCAP * sizeof(int), stream);   // -1 sentinels
    hipMemsetAsync(out, 0, (size_t)NTOK * DM * sizeof(float), stream);

    k_cast_x<<<NTOK * DM / 1024, 256, 0, stream>>>(x, xb);
    dim3 tb(32, 8);
    dim3 tg(32, 32, NE);
    k_transpose<<<tg, tb, 0, stream>>>(W1, w1t);
    k_transpose<<<tg, tb, 0, stream>>>(W2, w2t);
    k_gate<<<NTOK / 16, 256, 0, stream>>>(x, Wg, bg, tok_e, tok_w, counts);
    k_plan<<<1, 64, 0, stream>>>(counts, base, cursor, tile_e, tile_b, ntiles);
    k_fill<<<NTOK / 256, 256, 0, stream>>>(tok_e, tok_w, base, cursor, slot_token, slot_w);

    dim3 gg(DM / 128, MAXTILES);
    k_gemm<1><<<gg, 256, 0, stream>>>(xb, w1t, b1, slot_token, slot_w,
                                      tile_e, tile_b, ntiles, H, nullptr);
    k_gemm<2><<<gg, 256, 0, stream>>>(H, w2t, b2, slot_token, slot_w,
                                      tile_e, tile_b, ntiles, nullptr, out);
}

// Round 3
// 463.794 us; speedup vs baseline: 1.3986x; 1.1598x over previous
//
#include <hip/hip_runtime.h>
#include <hip/hip_bf16.h>

// MoE top-2, d=1024, E=8, N=8192 tokens. Grouped-GEMM design:
//   cast/transposes -> gate(top2) -> plan(pad slots to BM) -> fill -> GEMM1(relu) -> GEMM2(+atomic combine)
// R1: gate rewritten (transposed Wg LDS, float4) — 194us/1M conflicts -> fast.
// R2 post-mortem: staging DMA was lane-per-row => 64 strided lines/instr, FETCH 3x ideal,
//     MfmaUtil 7.8%. R3: chunked staging (8 rows x 128B per DMA instr, coalesced) with
//     XOR-swizzled LDS ([row][seg^row&7]) — coalesced global AND 2-way-free ds_read_b128.

#define NTOK   8192
#define DM     1024
#define NE     8
#define BM     128
#define NSLOT  (NTOK * 2)
#define PADCAP (NSLOT + NE * BM)      // 17408
#define MAXTILES (PADCAP / BM)        // 136

typedef __attribute__((ext_vector_type(8))) short  bf16x8;
typedef __attribute__((ext_vector_type(4))) float  f32x4;

__device__ __forceinline__ unsigned short f2bf(float f) {
    union { float f; unsigned u; } v; v.f = f;
    unsigned r = v.u + 0x7fffu + ((v.u >> 16) & 1u);
    return (unsigned short)(r >> 16);
}

// async global->LDS DMA, 16B per lane; dest = wave-uniform base + lane*16
__device__ __forceinline__ void load_lds16(const ushort* g, ushort* l) {
    __builtin_amdgcn_global_load_lds(
        (const __attribute__((address_space(1))) unsigned int*)g,
        (__attribute__((address_space(3))) unsigned int*)l,
        16, 0, 0);
}

// ---------- cast x (fp32 -> bf16), 4 elems/thread ----------
__global__ __launch_bounds__(256) void k_cast_x(const float* __restrict__ x,
                                                ushort* __restrict__ xb) {
    int i = blockIdx.x * 256 + threadIdx.x;   // i < NTOK*DM/4
    float4 v = ((const float4*)x)[i];
    ushort4 o;
    o.x = f2bf(v.x); o.y = f2bf(v.y); o.z = f2bf(v.z); o.w = f2bf(v.w);
    ((ushort4*)xb)[i] = o;
}

// ---------- transpose + cast weights: Wt[e][n][k] = W[e][k][n] ----------
__global__ __launch_bounds__(256) void k_transpose(const float* __restrict__ W,
                                                   ushort* __restrict__ Wt) {
    __shared__ float t[32][33];
    int e = blockIdx.z;
    const float* We = W + (size_t)e * DM * DM;
    ushort* Wte = Wt + (size_t)e * DM * DM;
    int kt = blockIdx.y * 32, nt = blockIdx.x * 32;
    int tx = threadIdx.x, ty = threadIdx.y;
#pragma unroll
    for (int i = 0; i < 4; i++) {
        int r = ty + i * 8;
        t[r][tx] = We[(size_t)(kt + r) * DM + nt + tx];
    }
    __syncthreads();
#pragma unroll
    for (int i = 0; i < 4; i++) {
        int r = ty + i * 8;
        Wte[(size_t)(nt + r) * DM + kt + tx] = f2bf(t[tx][r]);
    }
}

// ---------- gating: scores = x@Wg + bg (fp32 exact), top-2, counts ----------
// 4 waves/block, 4 tokens/wave -> 16 tokens/block, 512 blocks.
__global__ __launch_bounds__(256) void k_gate(const float* __restrict__ x,
                                              const float* __restrict__ Wg,
                                              const float* __restrict__ bg,
                                              int* __restrict__ tok_e,
                                              float* __restrict__ tok_w,
                                              int* __restrict__ counts) {
    __shared__ float wgT[NE][DM];   // 32 KB, transposed: wgT[e][d] = Wg[d][e]
    __shared__ int cnt[NE];
    int tid = threadIdx.x;
    if (tid < NE) cnt[tid] = 0;
    for (int i = tid; i < DM * NE; i += 256) {
        int d = i >> 3, e = i & 7;
        wgT[e][d] = Wg[i];
    }
    __syncthreads();
    int wave = tid >> 6, lane = tid & 63;
    int n0 = (blockIdx.x * 4 + wave) * 4;
    const float4* xr[4];
#pragma unroll
    for (int t = 0; t < 4; t++) xr[t] = (const float4*)(x + (size_t)(n0 + t) * DM);

    float acc[4][NE];
#pragma unroll
    for (int t = 0; t < 4; t++)
#pragma unroll
        for (int e = 0; e < NE; e++) acc[t][e] = 0.f;

#pragma unroll
    for (int j = 0; j < 4; j++) {
        float4 xv[4];
#pragma unroll
        for (int t = 0; t < 4; t++) xv[t] = xr[t][j * 64 + lane];
#pragma unroll
        for (int e = 0; e < NE; e++) {
            float4 wv = ((const float4*)&wgT[e][0])[j * 64 + lane];
#pragma unroll
            for (int t = 0; t < 4; t++) {
                acc[t][e] += xv[t].x * wv.x + xv[t].y * wv.y
                           + xv[t].z * wv.z + xv[t].w * wv.w;
            }
        }
    }
#pragma unroll
    for (int t = 0; t < 4; t++)
#pragma unroll
        for (int e = 0; e < NE; e++) {
#pragma unroll
            for (int off = 32; off >= 1; off >>= 1)
                acc[t][e] += __shfl_xor(acc[t][e], off);
        }
    if (lane < 4) {
        int t = lane, n = n0 + t;
        float sc[NE];
#pragma unroll
        for (int e = 0; e < NE; e++) sc[e] = acc[t][e] + bg[e];
        int e0 = 0; float v0 = sc[0];
#pragma unroll
        for (int e = 1; e < NE; e++) if (sc[e] > v0) { v0 = sc[e]; e0 = e; }
        int e1 = -1; float v1 = -3.0e38f;
#pragma unroll
        for (int e = 0; e < NE; e++) if (e != e0 && sc[e] > v1) { v1 = sc[e]; e1 = e; }
        tok_e[2 * n] = e0;     tok_w[2 * n] = v0;
        tok_e[2 * n + 1] = e1; tok_w[2 * n + 1] = v1;
        atomicAdd(&cnt[e0], 1);
        atomicAdd(&cnt[e1], 1);
    }
    __syncthreads();
    if (tid < NE) atomicAdd(&counts[tid], cnt[tid]);
}

// ---------- plan: padded bases + tile tables (serial, trivial) ----------
__global__ void k_plan(const int* __restrict__ counts, int* __restrict__ base,
                       int* __restrict__ cursor, int* __restrict__ tile_e,
                       int* __restrict__ tile_b, int* __restrict__ ntiles) {
    if (threadIdx.x == 0 && blockIdx.x == 0) {
        int off = 0, t = 0;
        for (int e = 0; e < NE; e++) {
            base[e] = off; cursor[e] = 0;
            int nt = (counts[e] + BM - 1) / BM;
            for (int i = 0; i < nt; i++) { tile_e[t] = e; tile_b[t] = off + i * BM; t++; }
            off += nt * BM;
        }
        *ntiles = t;
    }
}

// ---------- fill: scatter (token, weight) into expert slot ranges ----------
__global__ __launch_bounds__(256) void k_fill(const int* __restrict__ tok_e,
                                              const float* __restrict__ tok_w,
                                              const int* __restrict__ base,
                                              int* __restrict__ cursor,
                                              int* __restrict__ slot_token,
                                              float* __restrict__ slot_w) {
    int n = blockIdx.x * 256 + threadIdx.x;
#pragma unroll
    for (int k = 0; k < 2; k++) {
        int e = tok_e[2 * n + k];
        float w = tok_w[2 * n + k];
        int pos = atomicAdd(&cursor[e], 1);
        int s = base[e] + pos;
        slot_token[s] = n;
        slot_w[s] = w;
    }
}

// ---------- grouped GEMM: 128x128 tile, BK=64, 4 waves x (64x64 each) ----------
// Staging: chunk = 8 rows x 128B K-segment, one DMA instr per chunk:
//   lane l -> row l>>3, LDS seg-pos l&7, GLOBAL seg (l&7)^(l>>3)  [XOR swizzle]
//   => 8 full cache lines per instr (coalesced), dest = uniform + lane*16.
// LDS layout: As[row][seg_pos]*8 ushort, where seg_pos = g ^ (row&7).
// Fragment read (row, g=ks*4+quad): addr = row*64 + ((g^(row&7))*8) — 2 lanes/bank (free).
// PHASE 1: H = relu(Xg @ W1t^T + b1)   (store bf16)
// PHASE 2: out[token] += w * (H @ W2t^T + b2)   (fp32 atomicAdd)
template <int PHASE>
__global__ __launch_bounds__(256) void k_gemm(const ushort* __restrict__ A,
                                              const ushort* __restrict__ Wt,
                                              const float* __restrict__ bias,
                                              const int* __restrict__ slot_token,
                                              const float* __restrict__ slot_w,
                                              const int* __restrict__ tile_e,
                                              const int* __restrict__ tile_b,
                                              const int* __restrict__ ntiles,
                                              ushort* __restrict__ Hout,
                                              float* __restrict__ out) {
    int t = blockIdx.y;
    if (t >= *ntiles) return;
    int e = tile_e[t];
    int sbase = tile_b[t];
    int ncol0 = blockIdx.x * 128;

    __shared__ ushort AsL[8192];   // [row 0..127][64] xor-swizzled, 16 KB
    __shared__ ushort BsL[8192];

    int tid = threadIdx.x;
    int wave = tid >> 6, lane = tid & 63, quad = lane >> 4, lm = lane & 15;
    int wm = wave >> 1, wn = wave & 1;

    const ushort* Wte = Wt + (size_t)e * DM * DM;

    // staging decomposition: wave w covers chunks 4w..4w+3 (rows 32w..32w+31)
    int sr = lane >> 3;               // row within chunk, 0..7
    int sg = (lane & 7) ^ sr;         // GLOBAL segment this lane fetches (xor swizzle)
    const ushort* aptr[4];
    const ushort* bptr[4];
#pragma unroll
    for (int ci = 0; ci < 4; ci++) {
        int row = wave * 32 + ci * 8 + sr;
        int ar;
        if (PHASE == 1) {
            ar = slot_token[sbase + row];
            if (ar < 0) ar = 0;              // pad rows: load row 0, discard in epilogue
        } else {
            ar = sbase + row;
        }
        aptr[ci] = A + (size_t)ar * DM + sg * 8;
        bptr[ci] = Wte + (size_t)(ncol0 + row) * DM + sg * 8;
    }

    f32x4 acc[4][4];
#pragma unroll
    for (int i = 0; i < 4; i++)
#pragma unroll
        for (int j = 0; j < 4; j++) acc[i][j] = (f32x4){0.f, 0.f, 0.f, 0.f};

    for (int k0 = 0; k0 < DM; k0 += 64) {
#pragma unroll
        for (int ci = 0; ci < 4; ci++) {
            int cb = (wave * 4 + ci) * 512;   // chunk LDS base (ushorts)
            load_lds16(aptr[ci] + k0, &AsL[cb]);
            load_lds16(bptr[ci] + k0, &BsL[cb]);
        }
        __syncthreads();   // drains vmcnt: DMA complete, all waves staged
#pragma unroll
        for (int ks = 0; ks < 2; ks++) {
            bf16x8 av[4], bv[4];
            int g = ks * 4 + quad;
#pragma unroll
            for (int f = 0; f < 4; f++) {
                int ra = wm * 64 + f * 16 + lm;
                int rb = wn * 64 + f * 16 + lm;
                av[f] = *(const bf16x8*)&AsL[ra * 64 + ((g ^ (ra & 7)) * 8)];
                bv[f] = *(const bf16x8*)&BsL[rb * 64 + ((g ^ (rb & 7)) * 8)];
            }
#pragma unroll
            for (int fm = 0; fm < 4; fm++)
#pragma unroll
                for (int fn = 0; fn < 4; fn++)
                    acc[fm][fn] = __builtin_amdgcn_mfma_f32_16x16x32_bf16(
                        av[fm], bv[fn], acc[fm][fn], 0, 0, 0);
        }
        __syncthreads();   // readers done before next iteration's DMA overwrites
    }

    // epilogue — C/D layout: col = lane&15, row = quad*4 + r  [m89-verified]
#pragma unroll
    for (int fm = 0; fm < 4; fm++) {
        int rowg = wm * 64 + fm * 16 + quad * 4;
        if (PHASE == 1) {
#pragma unroll
            for (int fn = 0; fn < 4; fn++) {
                int col = ncol0 + wn * 64 + fn * 16 + lm;
                float bv2 = bias[e * DM + col];
#pragma unroll
                for (int r = 0; r < 4; r++) {
                    float v = acc[fm][fn][r] + bv2;
                    v = fmaxf(v, 0.f);
                    Hout[(size_t)(sbase + rowg + r) * DM + col] = f2bf(v);
                }
            }
        } else {
            int tk[4]; float wv[4];
#pragma unroll
            for (int r = 0; r < 4; r++) {
                tk[r] = slot_token[sbase + rowg + r];
                wv[r] = slot_w[sbase + rowg + r];
            }
#pragma unroll
            for (int fn = 0; fn < 4; fn++) {
                int col = ncol0 + wn * 64 + fn * 16 + lm;
                float bv2 = bias[e * DM + col];
#pragma unroll
                for (int r = 0; r < 4; r++) {
                    if (tk[r] >= 0) {
                        float v = wv[r] * (acc[fm][fn][r] + bv2);
                        atomicAdd(&out[(size_t)tk[r] * DM + col], v);
                    }
                }
            }
        }
    }
}

extern "C" void kernel_launch(void* const* d_in, const int* in_sizes, int n_in,
                              void* d_out, int out_size, void* d_ws, size_t ws_size,
                              hipStream_t stream) {
    const float* x  = (const float*)d_in[0];
    const float* Wg = (const float*)d_in[1];
    const float* bg = (const float*)d_in[2];
    const float* W1 = (const float*)d_in[3];
    const float* b1 = (const float*)d_in[4];
    const float* W2 = (const float*)d_in[5];
    const float* b2 = (const float*)d_in[6];
    float* out = (float*)d_out;

    char* ws = (char*)d_ws;
    // workspace layout (bytes) — total ~86.3 MB
    ushort* xb         = (ushort*)(ws + 0);            // 16 MB
    ushort* w1t        = (ushort*)(ws + 16777216);     // 16 MB
    ushort* w2t        = (ushort*)(ws + 33554432);     // 16 MB
    ushort* H          = (ushort*)(ws + 50331648);     // 34 MB (PADCAP*DM*2)
    int*    tok_e      = (int*)  (ws + 85983232);
    float*  tok_w      = (float*)(ws + 86048768);
    int*    slot_token = (int*)  (ws + 86114304);
    float*  slot_w     = (float*)(ws + 86183936);
    int*    counts     = (int*)  (ws + 86253568);
    int*    cursor     = counts + 8;
    int*    base       = counts + 16;
    int*    tile_e     = counts + 24;
    int*    tile_b     = tile_e + MAXTILES;
    int*    ntiles     = tile_b + MAXTILES;

    hipMemsetAsync(counts, 0, 16 * sizeof(int), stream);          // counts + cursor
    hipMemsetAsync(slot_token, 0xFF, PADCAP * sizeof(int), stream);   // -1 sentinels
    hipMemsetAsync(out, 0, (size_t)NTOK * DM * sizeof(float), stream);

    k_cast_x<<<NTOK * DM / 1024, 256, 0, stream>>>(x, xb);
    dim3 tb(32, 8);
    dim3 tg(32, 32, NE);
    k_transpose<<<tg, tb, 0, stream>>>(W1, w1t);
    k_transpose<<<tg, tb, 0, stream>>>(W2, w2t);
    k_gate<<<NTOK / 16, 256, 0, stream>>>(x, Wg, bg, tok_e, tok_w, counts);
    k_plan<<<1, 64, 0, stream>>>(counts, base, cursor, tile_e, tile_b, ntiles);
    k_fill<<<NTOK / 256, 256, 0, stream>>>(tok_e, tok_w, base, cursor, slot_token, slot_w);

    dim3 gg(DM / 128, MAXTILES);
    k_gemm<1><<<gg, 256, 0, stream>>>(xb, w1t, b1, slot_token, slot_w,
                                      tile_e, tile_b, ntiles, H, nullptr);
    k_gemm<2><<<gg, 256, 0, stream>>>(H, w2t, b2, slot_token, slot_w,
                                      tile_e, tile_b, ntiles, nullptr, out);
}

// Round 4
// 440.952 us; speedup vs baseline: 1.4710x; 1.0518x over previous
//
#include <hip/hip_runtime.h>
#include <hip/hip_bf16.h>

// MoE top-2, d=1024, E=8, N=8192 tokens. Grouped-GEMM design:
//   gate(top2 + x->bf16 cast) -> plan -> fill -> GEMM1(relu) -> GEMM2(+atomic combine)
// R1: gate rewrite (194us/1M conflicts -> fast). R3: coalesced chunked DMA staging.
// R4: k_gemm was latency-bound (MfmaUtil 10.5%, ~4600cyc/K-iter vs ~515 busy): the
//     __syncthreads vmcnt(0) drain serialized every K-iter. Now: BK=32 double-buffer
//     in same 32KB LDS, raw s_barrier + manual s_waitcnt vmcnt(4) -> prefetch stays
//     in flight across the barrier. Also: cast folded into gate, single fast transpose.

#define NTOK   8192
#define DM     1024
#define NE     8
#define BM     128
#define NSLOT  (NTOK * 2)
#define PADCAP (NSLOT + NE * BM)      // 17408
#define MAXTILES (PADCAP / BM)        // 136

typedef __attribute__((ext_vector_type(8))) short  bf16x8;
typedef __attribute__((ext_vector_type(4))) float  f32x4;
typedef __attribute__((ext_vector_type(8))) unsigned short u16x8;

__device__ __forceinline__ unsigned short f2bf(float f) {
    union { float f; unsigned u; } v; v.f = f;
    unsigned r = v.u + 0x7fffu + ((v.u >> 16) & 1u);
    return (unsigned short)(r >> 16);
}

// async global->LDS DMA, 16B per lane; dest = wave-uniform base + lane*16
__device__ __forceinline__ void load_lds16(const ushort* g, ushort* l) {
    __builtin_amdgcn_global_load_lds(
        (const __attribute__((address_space(1))) unsigned int*)g,
        (__attribute__((address_space(3))) unsigned int*)l,
        16, 0, 0);
}

// ---------- transpose + cast both weight tensors: Wt[e][n][k] = W[e][k][n] ----------
// 64x64 tiles, float4 reads, 16B bf16 stores. grid.z: 0..7 = W1, 8..15 = W2.
__global__ __launch_bounds__(256) void k_transpose2(const float* __restrict__ W1,
                                                    const float* __restrict__ W2,
                                                    ushort* __restrict__ w1t,
                                                    ushort* __restrict__ w2t) {
    int ez = blockIdx.z;
    const float* W = (ez < 8 ? W1 : W2) + (size_t)(ez & 7) * DM * DM;
    ushort* Wt = (ez < 8 ? w1t : w2t) + (size_t)(ez & 7) * DM * DM;
    __shared__ float t[64][65];
    int kt = blockIdx.y * 64, nt = blockIdx.x * 64;
    int tid = threadIdx.x;
    int r16 = tid >> 4, c4 = (tid & 15) * 4;
#pragma unroll
    for (int p = 0; p < 4; p++) {
        int k = p * 16 + r16;
        float4 v = *(const float4*)&W[(size_t)(kt + k) * DM + nt + c4];
        t[k][c4] = v.x; t[k][c4 + 1] = v.y; t[k][c4 + 2] = v.z; t[k][c4 + 3] = v.w;
    }
    __syncthreads();
    int n = tid >> 2, kb = (tid & 3) * 16;
#pragma unroll
    for (int h = 0; h < 2; h++) {
        int k0 = kb + h * 8;
        u16x8 o;
#pragma unroll
        for (int i = 0; i < 8; i++) o[i] = f2bf(t[k0 + i][n]);
        *(u16x8*)&Wt[(size_t)(nt + n) * DM + kt + k0] = o;
    }
}

// ---------- gating: scores = x@Wg + bg (fp32 exact), top-2, counts; also casts x->bf16 ----------
__global__ __launch_bounds__(256) void k_gate(const float* __restrict__ x,
                                              const float* __restrict__ Wg,
                                              const float* __restrict__ bg,
                                              ushort* __restrict__ xb,
                                              int* __restrict__ tok_e,
                                              float* __restrict__ tok_w,
                                              int* __restrict__ counts) {
    __shared__ float wgT[NE][DM];   // 32 KB, transposed: wgT[e][d] = Wg[d][e]
    __shared__ int cnt[NE];
    int tid = threadIdx.x;
    if (tid < NE) cnt[tid] = 0;
    for (int i = tid; i < DM * NE; i += 256) {
        int d = i >> 3, e = i & 7;
        wgT[e][d] = Wg[i];
    }
    __syncthreads();
    int wave = tid >> 6, lane = tid & 63;
    int n0 = (blockIdx.x * 4 + wave) * 4;
    const float4* xr[4];
#pragma unroll
    for (int t = 0; t < 4; t++) xr[t] = (const float4*)(x + (size_t)(n0 + t) * DM);

    float acc[4][NE];
#pragma unroll
    for (int t = 0; t < 4; t++)
#pragma unroll
        for (int e = 0; e < NE; e++) acc[t][e] = 0.f;

#pragma unroll
    for (int j = 0; j < 4; j++) {
        float4 xv[4];
#pragma unroll
        for (int t = 0; t < 4; t++) xv[t] = xr[t][j * 64 + lane];
        // fold the x -> bf16 cast into this pass (saves the separate cast kernel)
#pragma unroll
        for (int t = 0; t < 4; t++) {
            ushort4 o;
            o.x = f2bf(xv[t].x); o.y = f2bf(xv[t].y);
            o.z = f2bf(xv[t].z); o.w = f2bf(xv[t].w);
            ((ushort4*)xb)[(size_t)(n0 + t) * (DM / 4) + j * 64 + lane] = o;
        }
#pragma unroll
        for (int e = 0; e < NE; e++) {
            float4 wv = ((const float4*)&wgT[e][0])[j * 64 + lane];
#pragma unroll
            for (int t = 0; t < 4; t++) {
                acc[t][e] += xv[t].x * wv.x + xv[t].y * wv.y
                           + xv[t].z * wv.z + xv[t].w * wv.w;
            }
        }
    }
#pragma unroll
    for (int t = 0; t < 4; t++)
#pragma unroll
        for (int e = 0; e < NE; e++) {
#pragma unroll
            for (int off = 32; off >= 1; off >>= 1)
                acc[t][e] += __shfl_xor(acc[t][e], off);
        }
    if (lane < 4) {
        int t = lane, n = n0 + t;
        float sc[NE];
#pragma unroll
        for (int e = 0; e < NE; e++) sc[e] = acc[t][e] + bg[e];
        int e0 = 0; float v0 = sc[0];
#pragma unroll
        for (int e = 1; e < NE; e++) if (sc[e] > v0) { v0 = sc[e]; e0 = e; }
        int e1 = -1; float v1 = -3.0e38f;
#pragma unroll
        for (int e = 0; e < NE; e++) if (e != e0 && sc[e] > v1) { v1 = sc[e]; e1 = e; }
        tok_e[2 * n] = e0;     tok_w[2 * n] = v0;
        tok_e[2 * n + 1] = e1; tok_w[2 * n + 1] = v1;
        atomicAdd(&cnt[e0], 1);
        atomicAdd(&cnt[e1], 1);
    }
    __syncthreads();
    if (tid < NE) atomicAdd(&counts[tid], cnt[tid]);
}

// ---------- plan: padded bases + tile tables (serial, trivial) ----------
__global__ void k_plan(const int* __restrict__ counts, int* __restrict__ base,
                       int* __restrict__ cursor, int* __restrict__ tile_e,
                       int* __restrict__ tile_b, int* __restrict__ ntiles) {
    if (threadIdx.x == 0 && blockIdx.x == 0) {
        int off = 0, t = 0;
        for (int e = 0; e < NE; e++) {
            base[e] = off; cursor[e] = 0;
            int nt = (counts[e] + BM - 1) / BM;
            for (int i = 0; i < nt; i++) { tile_e[t] = e; tile_b[t] = off + i * BM; t++; }
            off += nt * BM;
        }
        *ntiles = t;
    }
}

// ---------- fill: scatter (token, weight) into expert slot ranges ----------
__global__ __launch_bounds__(256) void k_fill(const int* __restrict__ tok_e,
                                              const float* __restrict__ tok_w,
                                              const int* __restrict__ base,
                                              int* __restrict__ cursor,
                                              int* __restrict__ slot_token,
                                              float* __restrict__ slot_w) {
    int n = blockIdx.x * 256 + threadIdx.x;
#pragma unroll
    for (int k = 0; k < 2; k++) {
        int e = tok_e[2 * n + k];
        float w = tok_w[2 * n + k];
        int pos = atomicAdd(&cursor[e], 1);
        int s = base[e] + pos;
        slot_token[s] = n;
        slot_w[s] = w;
    }
}

// ---------- grouped GEMM: 128x128 tile, BK=32, double-buffered async pipeline ----------
// LDS per (buf, operand): [row 0..127][4 seg][8 ushort] = 8 KB; total 32 KB.
// DMA chunk = 16 rows x 64B: lane l -> row c*16+(l>>2), LDS seg l&3,
//   GLOBAL seg gseg = (l&3) ^ ((l>>4)&3)  [xor swizzle; dest stays uniform + l*16].
// Element (row, k=g*8+i) at seg_pos = g ^ ((row>>2)&3); fragment-read sel collapses
// to lane-constant quad ^ (lm>>2) -> conflict-free ds_read_b128.
// Pipeline: prefetch next buf, s_waitcnt vmcnt(4) (only the 4 OLDEST = current buf),
// raw s_barrier (no vmcnt(0) drain), 16 MFMA, s_barrier.
template <int PHASE>
__global__ __launch_bounds__(256) void k_gemm(const ushort* __restrict__ A,
                                              const ushort* __restrict__ Wt,
                                              const float* __restrict__ bias,
                                              const int* __restrict__ slot_token,
                                              const float* __restrict__ slot_w,
                                              const int* __restrict__ tile_e,
                                              const int* __restrict__ tile_b,
                                              const int* __restrict__ ntiles,
                                              ushort* __restrict__ Hout,
                                              float* __restrict__ out) {
    int t = blockIdx.y;
    if (t >= *ntiles) return;
    int e = tile_e[t];
    int sbase = tile_b[t];
    int ncol0 = blockIdx.x * 128;

    __shared__ ushort As[2][4096];   // [buf][row*32 + segpos*8]
    __shared__ ushort Bs[2][4096];

    int tid = threadIdx.x;
    int wave = tid >> 6, lane = tid & 63, quad = lane >> 4, lm = lane & 15;
    int wm = wave >> 1, wn = wave & 1;

    const ushort* Wte = Wt + (size_t)e * DM * DM;

    // staging: wave w covers chunks {2w, 2w+1} per operand (16 rows each)
    int sr = lane >> 2;                            // row-in-chunk 0..15
    int gseg = (lane & 3) ^ ((lane >> 4) & 3);     // global 16B-seg (xor swizzle)
    const ushort* aptr[2];
    const ushort* bptr[2];
#pragma unroll
    for (int ci = 0; ci < 2; ci++) {
        int row = (wave * 2 + ci) * 16 + sr;
        int ar;
        if (PHASE == 1) {
            ar = slot_token[sbase + row];
            if (ar < 0) ar = 0;              // pad rows: load row 0, discard in epilogue
        } else {
            ar = sbase + row;
        }
        aptr[ci] = A + (size_t)ar * DM + gseg * 8;
        bptr[ci] = Wte + (size_t)(ncol0 + row) * DM + gseg * 8;
    }

    f32x4 acc[4][4];
#pragma unroll
    for (int i = 0; i < 4; i++)
#pragma unroll
        for (int j = 0; j < 4; j++) acc[i][j] = (f32x4){0.f, 0.f, 0.f, 0.f};

    // fragment LDS offsets (ushort units): lane-constant swizzle sel
    int asel = ((quad ^ (lm >> 2)) & 3) * 8;
    int abase = (wm * 64 + lm) * 32 + asel;
    int bbase = (wn * 64 + lm) * 32 + asel;

#define ISSUE(buf, koff)                                          \
    do {                                                          \
        _Pragma("unroll")                                         \
        for (int ci = 0; ci < 2; ci++) {                          \
            int cb = (wave * 2 + ci) * 512;                       \
            load_lds16(aptr[ci] + (koff), &As[(buf)][cb]);        \
            load_lds16(bptr[ci] + (koff), &Bs[(buf)][cb]);        \
        }                                                         \
    } while (0)

    ISSUE(0, 0);
#pragma unroll 2
    for (int it = 0; it < 32; ++it) {
        if (it < 31) {
            ISSUE((it + 1) & 1, (it + 1) * 32);
            __builtin_amdgcn_s_waitcnt(0x0F74);   // vmcnt(4): current buf's 4 DMAs done
        } else {
            __builtin_amdgcn_s_waitcnt(0x0F70);   // vmcnt(0): last buf done
        }
        __builtin_amdgcn_s_barrier();
        const ushort* Ab = As[it & 1];
        const ushort* Bb = Bs[it & 1];
        bf16x8 av[4], bv[4];
#pragma unroll
        for (int f = 0; f < 4; f++) {
            av[f] = *(const bf16x8*)&Ab[abase + f * 512];
            bv[f] = *(const bf16x8*)&Bb[bbase + f * 512];
        }
#pragma unroll
        for (int fm = 0; fm < 4; fm++)
#pragma unroll
            for (int fn = 0; fn < 4; fn++)
                acc[fm][fn] = __builtin_amdgcn_mfma_f32_16x16x32_bf16(
                    av[fm], bv[fn], acc[fm][fn], 0, 0, 0);
        __builtin_amdgcn_s_barrier();   // readers done before this buf is re-staged
    }
#undef ISSUE

    // epilogue — C/D layout: col = lane&15, row = quad*4 + r  [m89-verified]
#pragma unroll
    for (int fm = 0; fm < 4; fm++) {
        int rowg = wm * 64 + fm * 16 + quad * 4;
        if (PHASE == 1) {
#pragma unroll
            for (int fn = 0; fn < 4; fn++) {
                int col = ncol0 + wn * 64 + fn * 16 + lm;
                float bv2 = bias[e * DM + col];
#pragma unroll
                for (int r = 0; r < 4; r++) {
                    float v = acc[fm][fn][r] + bv2;
                    v = fmaxf(v, 0.f);
                    Hout[(size_t)(sbase + rowg + r) * DM + col] = f2bf(v);
                }
            }
        } else {
            int tk[4]; float wv[4];
#pragma unroll
            for (int r = 0; r < 4; r++) {
                tk[r] = slot_token[sbase + rowg + r];
                wv[r] = slot_w[sbase + rowg + r];
            }
#pragma unroll
            for (int fn = 0; fn < 4; fn++) {
                int col = ncol0 + wn * 64 + fn * 16 + lm;
                float bv2 = bias[e * DM + col];
#pragma unroll
                for (int r = 0; r < 4; r++) {
                    if (tk[r] >= 0) {
                        float v = wv[r] * (acc[fm][fn][r] + bv2);
                        atomicAdd(&out[(size_t)tk[r] * DM + col], v);
                    }
                }
            }
        }
    }
}

extern "C" void kernel_launch(void* const* d_in, const int* in_sizes, int n_in,
                              void* d_out, int out_size, void* d_ws, size_t ws_size,
                              hipStream_t stream) {
    const float* x  = (const float*)d_in[0];
    const float* Wg = (const float*)d_in[1];
    const float* bg = (const float*)d_in[2];
    const float* W1 = (const float*)d_in[3];
    const float* b1 = (const float*)d_in[4];
    const float* W2 = (const float*)d_in[5];
    const float* b2 = (const float*)d_in[6];
    float* out = (float*)d_out;

    char* ws = (char*)d_ws;
    // workspace layout (bytes) — total ~86.3 MB
    ushort* xb         = (ushort*)(ws + 0);            // 16 MB
    ushort* w1t        = (ushort*)(ws + 16777216);     // 16 MB
    ushort* w2t        = (ushort*)(ws + 33554432);     // 16 MB
    ushort* H          = (ushort*)(ws + 50331648);     // 34 MB (PADCAP*DM*2)
    int*    tok_e      = (int*)  (ws + 85983232);
    float*  tok_w      = (float*)(ws + 86048768);
    int*    slot_token = (int*)  (ws + 86114304);
    float*  slot_w     = (float*)(ws + 86183936);
    int*    counts     = (int*)  (ws + 86253568);
    int*    cursor     = counts + 8;
    int*    base       = counts + 16;
    int*    tile_e     = counts + 24;
    int*    tile_b     = tile_e + MAXTILES;
    int*    ntiles     = tile_b + MAXTILES;

    hipMemsetAsync(counts, 0, 16 * sizeof(int), stream);              // counts + cursor
    hipMemsetAsync(slot_token, 0xFF, PADCAP * sizeof(int), stream);   // -1 sentinels
    hipMemsetAsync(out, 0, (size_t)NTOK * DM * sizeof(float), stream);

    dim3 tg(16, 16, 16);
    k_transpose2<<<tg, 256, 0, stream>>>(W1, W2, w1t, w2t);
    k_gate<<<NTOK / 16, 256, 0, stream>>>(x, Wg, bg, xb, tok_e, tok_w, counts);
    k_plan<<<1, 64, 0, stream>>>(counts, base, cursor, tile_e, tile_b, ntiles);
    k_fill<<<NTOK / 256, 256, 0, stream>>>(tok_e, tok_w, base, cursor, slot_token, slot_w);

    dim3 gg(DM / 128, MAXTILES);
    k_gemm<1><<<gg, 256, 0, stream>>>(xb, w1t, b1, slot_token, slot_w,
                                      tile_e, tile_b, ntiles, H, nullptr);
    k_gemm<2><<<gg, 256, 0, stream>>>(H, w2t, b2, slot_token, slot_w,
                                      tile_e, tile_b, ntiles, nullptr, out);
}